// Round 13
// baseline (230.062 us; speedup 1.0000x reference)
//
#include <hip/hip_runtime.h>

using u16 = unsigned short;
using u32 = unsigned int;

typedef __bf16 bf16x8 __attribute__((ext_vector_type(8)));
typedef float  f32x4  __attribute__((ext_vector_type(4)));
typedef float  f32x8  __attribute__((ext_vector_type(8)));
typedef float  f32x16 __attribute__((ext_vector_type(16)));
typedef u16    u16x8  __attribute__((ext_vector_type(8)));
typedef u32    u32x4  __attribute__((ext_vector_type(4)));

// fast exp: hardware exp2 via compiler-visible builtin (TRANS hazards handled)
#if __has_builtin(__builtin_amdgcn_exp2f)
#define QSCALE 0.1803368801f  /* 0.125 * log2(e) */
__device__ __forceinline__ float fexp(float x) { return __builtin_amdgcn_exp2f(x); }
#else
#define QSCALE 0.125f
__device__ __forceinline__ float fexp(float x) { return __expf(x); }
#endif

__device__ __forceinline__ u32 f2bf(float f) {
  u32 u = __builtin_bit_cast(u32, f);
  return (u + 0x7fffu + ((u >> 16) & 1u)) >> 16;
}

__device__ __forceinline__ void gload_lds16(const u16* g, u16* lds) {
  __builtin_amdgcn_global_load_lds(
      (const __attribute__((address_space(1))) void*)g,
      (__attribute__((address_space(3))) void*)lds, 16, 0, 0);
}

__device__ __forceinline__ u32 cvtpk(float lo, float hi) {
  u32 r;
  asm("v_cvt_pk_bf16_f32 %0, %1, %2" : "=v"(r) : "v"(lo), "v"(hi));
  return r;
}

__device__ __forceinline__ float xhalf_add(float v) {
  return v + __shfl_xor(v, 32);
}

// ---------------------------------------------------------------------------
// fp32 -> bf16 conversion of x + Wq/Wk/Wv/Wo (16 elems/thread)
// ---------------------------------------------------------------------------
__global__ __launch_bounds__(256) void cvt_all(
    const float* __restrict__ x,  const float* __restrict__ wq,
    const float* __restrict__ wk, const float* __restrict__ wv,
    const float* __restrict__ wo, u16* __restrict__ out) {
  size_t i = ((size_t)blockIdx.x * 256 + threadIdx.x) * 16;
  const float* src;
  if (i < 4194304) {
    src = x + i;
  } else {
    size_t j = i - 4194304;
    unsigned w = (unsigned)(j >> 20);
    size_t o = j & 1048575;
    src = (w == 0) ? (wq + o) : (w == 1) ? (wk + o) : (w == 2) ? (wv + o) : (wo + o);
  }
  f32x4 a = *(const f32x4*)src;
  f32x4 b = *(const f32x4*)(src + 4);
  f32x4 c = *(const f32x4*)(src + 8);
  f32x4 d = *(const f32x4*)(src + 12);
  u32x4 r0, r1;
  r0[0] = f2bf(a[0]) | (f2bf(a[1]) << 16);
  r0[1] = f2bf(a[2]) | (f2bf(a[3]) << 16);
  r0[2] = f2bf(b[0]) | (f2bf(b[1]) << 16);
  r0[3] = f2bf(b[2]) | (f2bf(b[3]) << 16);
  r1[0] = f2bf(c[0]) | (f2bf(c[1]) << 16);
  r1[1] = f2bf(c[2]) | (f2bf(c[3]) << 16);
  r1[2] = f2bf(d[0]) | (f2bf(d[1]) << 16);
  r1[3] = f2bf(d[2]) | (f2bf(d[3]) << 16);
  *(u32x4*)(out + i) = r0;
  *(u32x4*)(out + i + 8) = r1;
}

// ---------------------------------------------------------------------------
// C[M,N] = A[M,K] * B[N,K]^T. BM in {128, 64}.
// ---------------------------------------------------------------------------
template <bool F32OUT, int BM>
__device__ __forceinline__ void gemm_tile(const u16* __restrict__ A,
                                          const u16* __restrict__ Bm,
                                          void* __restrict__ Cv,
                                          int rowBase, int colBase, float scale) {
  __shared__ __align__(16) u16 As[BM * 64];
  __shared__ __align__(16) u16 Bs[128 * 64];

  const int t = threadIdx.x;
  const int lane = t & 63;
  const int wv = t >> 6;
  const int wr = (wv >> 1) * (BM / 2);
  const int wc = (wv & 1) * 64;
  const int l15 = lane & 15;
  const int lg = lane >> 4;

  f32x4 acc[BM / 32][4] = {};

  for (int kt = 0; kt < 1024; kt += 64) {
#pragma unroll
    for (int i = 0; i < BM / 32; ++i) {
      int s = i * 256 + t;
      int row = s >> 3;
      int k2 = (s & 7) ^ (row & 7);
      gload_lds16(A + (size_t)(rowBase + row) * 1024 + kt + k2 * 8,
                  &As[(i * 256 + wv * 64) * 8]);
    }
#pragma unroll
    for (int i = 0; i < 4; ++i) {
      int s = i * 256 + t;
      int row = s >> 3;
      int k2 = (s & 7) ^ (row & 7);
      gload_lds16(Bm + (size_t)(colBase + row) * 1024 + kt + k2 * 8,
                  &Bs[(i * 256 + wv * 64) * 8]);
    }
    __syncthreads();
#pragma unroll
    for (int kk = 0; kk < 2; ++kk) {
      bf16x8 af[BM / 32], bfr[4];
#pragma unroll
      for (int m = 0; m < BM / 32; ++m) {
        int row = wr + m * 16 + l15;
        af[m] = *(const bf16x8*)&As[row * 64 + (((kk * 4 + lg) ^ (row & 7)) * 8)];
      }
#pragma unroll
      for (int n = 0; n < 4; ++n) {
        int row = wc + n * 16 + l15;
        bfr[n] = *(const bf16x8*)&Bs[row * 64 + (((kk * 4 + lg) ^ (row & 7)) * 8)];
      }
      __builtin_amdgcn_s_setprio(1);
#pragma unroll
      for (int m = 0; m < BM / 32; ++m)
#pragma unroll
        for (int n = 0; n < 4; ++n)
          acc[m][n] = __builtin_amdgcn_mfma_f32_16x16x32_bf16(af[m], bfr[n], acc[m][n], 0, 0, 0);
      __builtin_amdgcn_s_setprio(0);
    }
    __syncthreads();
  }

#pragma unroll
  for (int m = 0; m < BM / 32; ++m) {
#pragma unroll
    for (int r = 0; r < 4; ++r) {
      int row = rowBase + wr + m * 16 + lg * 4 + r;
#pragma unroll
      for (int n = 0; n < 4; ++n) {
        int col = colBase + wc + n * 16 + l15;
        float v = acc[m][n][r] * scale;
        if (F32OUT)
          ((float*)Cv)[(size_t)row * 1024 + col] = v;
        else
          ((u16*)Cv)[(size_t)row * 1024 + col] = (u16)f2bf(v);
      }
    }
  }
}

__global__ __launch_bounds__(256) void gemm_qkv(
    const u16* __restrict__ xb,
    const u16* __restrict__ wq, const u16* __restrict__ wk, const u16* __restrict__ wv,
    u16* __restrict__ Qm, u16* __restrict__ Km, u16* __restrict__ Vm) {
  int bx = blockIdx.x;
  int mat = bx >> 8;
  int rem = bx & 255;
  int bm = rem & 31, bn = rem >> 5;
  const u16* B = (mat == 0) ? wq : (mat == 1) ? wk : wv;
  u16* C = (mat == 0) ? Qm : (mat == 1) ? Km : Vm;
  float scale = (mat == 0) ? QSCALE : 1.0f;
  gemm_tile<false, 128>(xb, B, C, bm * 128, bn * 128, scale);
}

__global__ __launch_bounds__(256) void gemm_out(
    const u16* __restrict__ ao, const u16* __restrict__ wo, float* __restrict__ C) {
  int bm = blockIdx.x & 63, bn = blockIdx.x >> 6;
  gemm_tile<true, 64>(ao, wo, C, bm * 64, bn * 128, 1.0f);
}

// ---------------------------------------------------------------------------
// Flash attention v13 = v12 pipeline with the in-block kv-split REMOVED:
// one 4-wave (256-thr) block owns all 2048 kv (32 iters). LDS 80->40 KB ->
// 4 blocks/CU = 4 independent barrier domains (was 2): when one block drains
// at its barrier, three others issue. Same counted-vmcnt schedule, same
// 3-buffer V / 2-buffer K, pa ping-pong. Combine epilogue deleted.
// ---------------------------------------------------------------------------
__global__ __launch_bounds__(256, 4) void attn_fwd(
    const u16* __restrict__ Q, const u16* __restrict__ K,
    const u16* __restrict__ V, u16* __restrict__ AO) {
  __shared__ __align__(16) u16 Ks[2][64 * 64];   // [buf][kv][d] swz key=row&7
  __shared__ __align__(16) u16 Vt3[3][64 * 64];  // [buf][d][kv-perm]

  const int t = threadIdx.x;
  const int lane = t & 63;
  const int wg = t >> 6;        // 0..3
  const int l31 = lane & 31;
  const int hi = lane >> 5;

  const int qb = blockIdx.x;
  const int pr = blockIdx.y;
  const size_t hb = (size_t)(pr >> 4) * 2048 * 1024 + (size_t)(pr & 15) * 64;
  const u16* Qh = Q + hb;
  const u16* Kh = K + hb;
  const u16* Vh = V + hb;
  u16* AOh = AO + hb;

  const int q0w = qb * 128 + wg * 32;

  bf16x8 qf[4];
#pragma unroll
  for (int kk = 0; kk < 4; ++kk)
    qf[kk] = *(const bf16x8*)&Qh[(size_t)(q0w + l31) * 1024 + kk * 16 + hi * 8];

  f32x16 ot[2] = {};
  f32x16 sc[2];
  f32x8  Lacc = {};
  bf16x8 pa0[4], pa1[4];

  const int kxor = l31 & 7;
  const int kd0 = (l31 & 7) ^ (l31 >> 3);
  const int kv0 = (t >> 3) * 2, d0 = (t & 7) * 8;
  const int vg = (kv0 >> 4) * 2 + ((kv0 >> 2) & 1);
  const int vj = (kv0 & 3) + ((kv0 >> 3) & 1) * 4;

  auto VLOAD = [&](int tile, u16x8& a, u16x8& b) {
    a = *(const u16x8*)&Vh[(size_t)(tile * 64 + kv0) * 1024 + d0];
    b = *(const u16x8*)&Vh[(size_t)(tile * 64 + kv0 + 1) * 1024 + d0];
  };
  auto KSTAGE = [&](int tile, int buf) {
#pragma unroll
    for (int i = 0; i < 2; ++i) {
      int s = i * 256 + t;
      int krow = s >> 3;
      int k2 = (s & 7) ^ (krow & 7);
      gload_lds16(&Kh[(size_t)(tile * 64 + krow) * 1024 + k2 * 8],
                  &Ks[buf][(i * 256 + wg * 64) * 8]);
    }
  };
  auto VPACK = [&](u16x8 a, u16x8 b, u16* dst) {
#pragma unroll
    for (int e = 0; e < 8; ++e) {
      int d = d0 + e;
      int key = ((d & 7) ^ (d >> 3)) & 7;
      int idx = d * 64 + ((vg ^ key) * 8) + vj;
      *(u32*)&dst[idx] = (u32)a[e] | ((u32)b[e] << 16);
    }
  };
  auto QKT = [&](const u16* ks) {
    sc[0] = f32x16{};
    sc[1] = f32x16{};
    __builtin_amdgcn_s_setprio(1);
#pragma unroll
    for (int kk = 0; kk < 4; ++kk) {
      bf16x8 kf0 = *(const bf16x8*)&ks[l31 * 64 + (((kk * 2 + hi) ^ kxor) * 8)];
      bf16x8 kf1 = *(const bf16x8*)&ks[(32 + l31) * 64 + (((kk * 2 + hi) ^ kxor) * 8)];
      sc[0] = __builtin_amdgcn_mfma_f32_32x32x16_bf16(kf0, qf[kk], sc[0], 0, 0, 0);
      sc[1] = __builtin_amdgcn_mfma_f32_32x32x16_bf16(kf1, qf[kk], sc[1], 0, 0, 0);
    }
    __builtin_amdgcn_s_setprio(0);
  };
  auto PV = [&](const u16* vt, const bf16x8* pa) {
    __builtin_amdgcn_s_setprio(1);
#pragma unroll
    for (int kk = 0; kk < 4; ++kk) {
      bf16x8 vf0 = *(const bf16x8*)&vt[l31 * 64 + (((kk * 2 + hi) ^ kd0) * 8)];
      bf16x8 vf1 = *(const bf16x8*)&vt[(32 + l31) * 64 + (((kk * 2 + hi) ^ (kd0 ^ 4)) * 8)];
      ot[0] = __builtin_amdgcn_mfma_f32_32x32x16_bf16(vf0, pa[kk], ot[0], 0, 0, 0);
      ot[1] = __builtin_amdgcn_mfma_f32_32x32x16_bf16(vf1, pa[kk], ot[1], 0, 0, 0);
    }
    __builtin_amdgcn_s_setprio(0);
  };
  auto EXPPACK = [&](bf16x8* pa) {
#pragma unroll
    for (int fi = 0; fi < 2; ++fi)
#pragma unroll
      for (int r = 0; r < 16; ++r)
        sc[fi][r] = fexp(sc[fi][r]);
    {
      f32x8 lo0 = __builtin_shufflevector(sc[0], sc[0], 0,1,2,3,4,5,6,7);
      f32x8 hi0 = __builtin_shufflevector(sc[0], sc[0], 8,9,10,11,12,13,14,15);
      f32x8 lo1 = __builtin_shufflevector(sc[1], sc[1], 0,1,2,3,4,5,6,7);
      f32x8 hi1 = __builtin_shufflevector(sc[1], sc[1], 8,9,10,11,12,13,14,15);
      Lacc += (lo0 + hi0) + (lo1 + hi1);
    }
#pragma unroll
    for (int fi = 0; fi < 2; ++fi) {
      u32x4 w0 = {cvtpk(sc[fi][0],  sc[fi][1]),  cvtpk(sc[fi][2],  sc[fi][3]),
                  cvtpk(sc[fi][4],  sc[fi][5]),  cvtpk(sc[fi][6],  sc[fi][7])};
      u32x4 w1 = {cvtpk(sc[fi][8],  sc[fi][9]),  cvtpk(sc[fi][10], sc[fi][11]),
                  cvtpk(sc[fi][12], sc[fi][13]), cvtpk(sc[fi][14], sc[fi][15])};
      pa[2 * fi]     = __builtin_bit_cast(bf16x8, w0);
      pa[2 * fi + 1] = __builtin_bit_cast(bf16x8, w1);
    }
  };

  int vm1 = 2, v0 = 0, vp1 = 1;
  auto ROT = [&]() { int tmp = vm1; vm1 = v0; v0 = vp1; vp1 = tmp; };

  // ---- prologue: V[0] regs (oldest), K[0], K[1]; pack V[0]->buf0; S[0] ----
  {
    u16x8 a, b;
    VLOAD(0, a, b);
    __builtin_amdgcn_sched_barrier(0);
    KSTAGE(0, 0);
    KSTAGE(1, 1);
    VPACK(a, b, &Vt3[0][0]);                            // compiler waits vmcnt(4)
    asm volatile("s_waitcnt vmcnt(2)" ::: "memory");    // K[0] landed
    asm volatile("s_waitcnt lgkmcnt(0)" ::: "memory");
    __builtin_amdgcn_sched_barrier(0);
    __builtin_amdgcn_s_barrier();
    QKT(&Ks[0][0]);                                     // S[0]
    asm volatile("s_waitcnt lgkmcnt(0)" ::: "memory");
    __builtin_amdgcn_sched_barrier(0);
    __builtin_amdgcn_s_barrier();
  }

  // ---- steady loop: tt = 0..29 ----
  for (int tp = 0; tp < 15; ++tp) {
#pragma unroll
    for (int sub = 0; sub < 2; ++sub) {
      const int tt = 2 * tp + sub;
      u16x8 a, b;
      VLOAD(tt + 1, a, b);                              // oldest this iter
      __builtin_amdgcn_sched_barrier(0);
      KSTAGE(tt + 2, sub);                              // in flight across barrier
      if (tt >= 1) PV(&Vt3[vm1][0], sub ? pa0 : pa1);
      EXPPACK(sub ? pa1 : pa0);
      asm volatile("s_waitcnt vmcnt(4)" ::: "memory");  // K[tt+1] landed
      QKT(&Ks[sub ^ 1][0]);                             // S[tt+1]
      VPACK(a, b, &Vt3[vp1][0]);                        // compiler waits vmcnt(2)
      asm volatile("s_waitcnt lgkmcnt(0)" ::: "memory");
      __builtin_amdgcn_sched_barrier(0);
      __builtin_amdgcn_s_barrier();
      ROT();
    }
  }

  // ---- iter 30 (sub=0): no K prefetch ----
  {
    u16x8 a, b;
    VLOAD(31, a, b);
    __builtin_amdgcn_sched_barrier(0);
    PV(&Vt3[vm1][0], pa1);
    EXPPACK(pa0);
    asm volatile("s_waitcnt vmcnt(2)" ::: "memory");    // K[31] landed
    QKT(&Ks[1][0]);                                     // S[31]
    VPACK(a, b, &Vt3[vp1][0]);                          // compiler waits vmcnt(0)
    asm volatile("s_waitcnt lgkmcnt(0)" ::: "memory");
    __builtin_amdgcn_sched_barrier(0);
    __builtin_amdgcn_s_barrier();
    ROT();
  }
  // ---- iter 31 (sub=1): PV(30), exp/pack(31) ----
  PV(&Vt3[vm1][0], pa0);
  EXPPACK(pa1);
  ROT();
  // ---- final PV: P[31] x V[31] ----
  PV(&Vt3[vm1][0], pa1);

  // ---- epilogue: L reduce, normalize, store ----
  float lp = (((Lacc[0] + Lacc[1]) + (Lacc[2] + Lacc[3])) +
              ((Lacc[4] + Lacc[5]) + (Lacc[6] + Lacc[7])));
  float L = xhalf_add(lp);
  float inv = 1.f / L;
  const size_t qrow = (size_t)(q0w + l31) * 1024;
#pragma unroll
  for (int dn = 0; dn < 2; ++dn)
#pragma unroll
    for (int j = 0; j < 8; ++j) {
      int r = 2 * j;
      int d = 2 * (j & 1) + 8 * (j >> 1) + 4 * hi + 32 * dn;
      u32 w = cvtpk(ot[dn][r] * inv, ot[dn][r + 1] * inv);
      *(u32*)&AOh[qrow + d] = w;
    }
}

// ---------------------------------------------------------------------------
extern "C" void kernel_launch(void* const* d_in, const int* in_sizes, int n_in,
                              void* d_out, int out_size, void* d_ws, size_t ws_size,
                              hipStream_t stream) {
  const float* x  = (const float*)d_in[0];
  const float* wq = (const float*)d_in[1];
  const float* wk = (const float*)d_in[2];
  const float* wv = (const float*)d_in[3];
  const float* wo = (const float*)d_in[4];

  u16* ws = (u16*)d_ws;
  u16* xb  = ws;                 // 4194304  (x bf16)
  u16* wqb = ws + 4194304;       // 1048576
  u16* wkb = ws + 5242880;
  u16* wvb = ws + 6291456;
  u16* wob = ws + 7340032;
  u16* Qm  = ws + 8388608;       // 4194304
  u16* Km  = ws + 12582912;
  u16* Vm  = ws + 16777216;      // 4194304 (row-major V)
  u16* AOm = ws + 20971520;      // end at 25165824 u16 = 48 MiB

  cvt_all<<<2048, 256, 0, stream>>>(x, wq, wk, wv, wo, ws);
  gemm_qkv<<<768, 256, 0, stream>>>(xb, wqb, wkb, wvb, Qm, Km, Vm);
  attn_fwd<<<dim3(16, 32), 256, 0, stream>>>(Qm, Km, Vm, AOm);
  gemm_out<<<512, 256, 0, stream>>>(AOm, wob, (float*)d_out);
}

// Round 14
// 105.580 us; speedup vs baseline: 2.1790x; 2.1790x over previous
//
#include <hip/hip_runtime.h>

using u16 = unsigned short;
using u32 = unsigned int;

typedef __bf16 bf16x8 __attribute__((ext_vector_type(8)));
typedef float  f32x4  __attribute__((ext_vector_type(4)));
typedef float  f32x8  __attribute__((ext_vector_type(8)));
typedef float  f32x16 __attribute__((ext_vector_type(16)));
typedef u16    u16x8  __attribute__((ext_vector_type(8)));
typedef u32    u32x4  __attribute__((ext_vector_type(4)));

// fast exp: hardware exp2 via compiler-visible builtin (TRANS hazards handled)
#if __has_builtin(__builtin_amdgcn_exp2f)
#define QSCALE 0.1803368801f  /* 0.125 * log2(e) */
__device__ __forceinline__ float fexp(float x) { return __builtin_amdgcn_exp2f(x); }
#else
#define QSCALE 0.125f
__device__ __forceinline__ float fexp(float x) { return __expf(x); }
#endif

__device__ __forceinline__ u32 f2bf(float f) {
  u32 u = __builtin_bit_cast(u32, f);
  return (u + 0x7fffu + ((u >> 16) & 1u)) >> 16;
}

__device__ __forceinline__ void gload_lds16(const u16* g, u16* lds) {
  __builtin_amdgcn_global_load_lds(
      (const __attribute__((address_space(1))) void*)g,
      (__attribute__((address_space(3))) void*)lds, 16, 0, 0);
}

__device__ __forceinline__ u32 cvtpk(float lo, float hi) {
  u32 r;
  asm("v_cvt_pk_bf16_f32 %0, %1, %2" : "=v"(r) : "v"(lo), "v"(hi));
  return r;
}

__device__ __forceinline__ float xhalf_add(float v) {
  return v + __shfl_xor(v, 32);
}

// ---------------------------------------------------------------------------
// fp32 -> bf16 conversion of x + Wq/Wk/Wv/Wo (16 elems/thread)
// ---------------------------------------------------------------------------
__global__ __launch_bounds__(256) void cvt_all(
    const float* __restrict__ x,  const float* __restrict__ wq,
    const float* __restrict__ wk, const float* __restrict__ wv,
    const float* __restrict__ wo, u16* __restrict__ out) {
  size_t i = ((size_t)blockIdx.x * 256 + threadIdx.x) * 16;
  const float* src;
  if (i < 4194304) {
    src = x + i;
  } else {
    size_t j = i - 4194304;
    unsigned w = (unsigned)(j >> 20);
    size_t o = j & 1048575;
    src = (w == 0) ? (wq + o) : (w == 1) ? (wk + o) : (w == 2) ? (wv + o) : (wo + o);
  }
  f32x4 a = *(const f32x4*)src;
  f32x4 b = *(const f32x4*)(src + 4);
  f32x4 c = *(const f32x4*)(src + 8);
  f32x4 d = *(const f32x4*)(src + 12);
  u32x4 r0, r1;
  r0[0] = f2bf(a[0]) | (f2bf(a[1]) << 16);
  r0[1] = f2bf(a[2]) | (f2bf(a[3]) << 16);
  r0[2] = f2bf(b[0]) | (f2bf(b[1]) << 16);
  r0[3] = f2bf(b[2]) | (f2bf(b[3]) << 16);
  r1[0] = f2bf(c[0]) | (f2bf(c[1]) << 16);
  r1[1] = f2bf(c[2]) | (f2bf(c[3]) << 16);
  r1[2] = f2bf(d[0]) | (f2bf(d[1]) << 16);
  r1[3] = f2bf(d[2]) | (f2bf(d[3]) << 16);
  *(u32x4*)(out + i) = r0;
  *(u32x4*)(out + i + 8) = r1;
}

// ---------------------------------------------------------------------------
// C[M,N] = A[M,K] * B[N,K]^T. BM in {128, 64}.
// ---------------------------------------------------------------------------
template <bool F32OUT, int BM>
__device__ __forceinline__ void gemm_tile(const u16* __restrict__ A,
                                          const u16* __restrict__ Bm,
                                          void* __restrict__ Cv,
                                          int rowBase, int colBase, float scale) {
  __shared__ __align__(16) u16 As[BM * 64];
  __shared__ __align__(16) u16 Bs[128 * 64];

  const int t = threadIdx.x;
  const int lane = t & 63;
  const int wv = t >> 6;
  const int wr = (wv >> 1) * (BM / 2);
  const int wc = (wv & 1) * 64;
  const int l15 = lane & 15;
  const int lg = lane >> 4;

  f32x4 acc[BM / 32][4] = {};

  for (int kt = 0; kt < 1024; kt += 64) {
#pragma unroll
    for (int i = 0; i < BM / 32; ++i) {
      int s = i * 256 + t;
      int row = s >> 3;
      int k2 = (s & 7) ^ (row & 7);
      gload_lds16(A + (size_t)(rowBase + row) * 1024 + kt + k2 * 8,
                  &As[(i * 256 + wv * 64) * 8]);
    }
#pragma unroll
    for (int i = 0; i < 4; ++i) {
      int s = i * 256 + t;
      int row = s >> 3;
      int k2 = (s & 7) ^ (row & 7);
      gload_lds16(Bm + (size_t)(colBase + row) * 1024 + kt + k2 * 8,
                  &Bs[(i * 256 + wv * 64) * 8]);
    }
    __syncthreads();
#pragma unroll
    for (int kk = 0; kk < 2; ++kk) {
      bf16x8 af[BM / 32], bfr[4];
#pragma unroll
      for (int m = 0; m < BM / 32; ++m) {
        int row = wr + m * 16 + l15;
        af[m] = *(const bf16x8*)&As[row * 64 + (((kk * 4 + lg) ^ (row & 7)) * 8)];
      }
#pragma unroll
      for (int n = 0; n < 4; ++n) {
        int row = wc + n * 16 + l15;
        bfr[n] = *(const bf16x8*)&Bs[row * 64 + (((kk * 4 + lg) ^ (row & 7)) * 8)];
      }
      __builtin_amdgcn_s_setprio(1);
#pragma unroll
      for (int m = 0; m < BM / 32; ++m)
#pragma unroll
        for (int n = 0; n < 4; ++n)
          acc[m][n] = __builtin_amdgcn_mfma_f32_16x16x32_bf16(af[m], bfr[n], acc[m][n], 0, 0, 0);
      __builtin_amdgcn_s_setprio(0);
    }
    __syncthreads();
  }

#pragma unroll
  for (int m = 0; m < BM / 32; ++m) {
#pragma unroll
    for (int r = 0; r < 4; ++r) {
      int row = rowBase + wr + m * 16 + lg * 4 + r;
#pragma unroll
      for (int n = 0; n < 4; ++n) {
        int col = colBase + wc + n * 16 + l15;
        float v = acc[m][n][r] * scale;
        if (F32OUT)
          ((float*)Cv)[(size_t)row * 1024 + col] = v;
        else
          ((u16*)Cv)[(size_t)row * 1024 + col] = (u16)f2bf(v);
      }
    }
  }
}

__global__ __launch_bounds__(256) void gemm_qkv(
    const u16* __restrict__ xb,
    const u16* __restrict__ wq, const u16* __restrict__ wk, const u16* __restrict__ wv,
    u16* __restrict__ Qm, u16* __restrict__ Km, u16* __restrict__ Vm) {
  int bx = blockIdx.x;
  int mat = bx >> 8;
  int rem = bx & 255;
  int bm = rem & 31, bn = rem >> 5;
  const u16* B = (mat == 0) ? wq : (mat == 1) ? wk : wv;
  u16* C = (mat == 0) ? Qm : (mat == 1) ? Km : Vm;
  float scale = (mat == 0) ? QSCALE : 1.0f;
  gemm_tile<false, 128>(xb, B, C, bm * 128, bn * 128, scale);
}

__global__ __launch_bounds__(256) void gemm_out(
    const u16* __restrict__ ao, const u16* __restrict__ wo, float* __restrict__ C) {
  int bm = blockIdx.x & 63, bn = blockIdx.x >> 6;
  gemm_tile<true, 64>(ao, wo, C, bm * 64, bn * 128, 1.0f);
}

// ---------------------------------------------------------------------------
// Flash attention v14 = v12 (8-wave, in-block kv-split, counted-vmcnt
// pipeline — measured 52.7 us) + T1 XCD-aware block swizzle: 1-D grid,
// block b -> pr=(b&7)*4+((b>>3)&3), qb=b>>5, so each XCD's L2 serves the
// K/V of exactly 4 heads (2 MB working set vs ~4+ MB thrashing before).
// ---------------------------------------------------------------------------
__global__ __launch_bounds__(512, 2) void attn_fwd(
    const u16* __restrict__ Q, const u16* __restrict__ K,
    const u16* __restrict__ V, u16* __restrict__ AO) {
  __shared__ __align__(16) u16 Ks[2][2][64 * 64];   // [grp][buf][kv][d] swz key=row&7
  __shared__ __align__(16) u16 Vt3[2][3][64 * 64];  // [grp][buf][d][kv-perm]

  const int t = threadIdx.x;
  const int lane = t & 63;
  const int wvi = t >> 6;
  const int wg = wvi & 3;
  const int grp = wvi >> 2;
  const int tg = t & 255;
  const int l31 = lane & 31;
  const int hi = lane >> 5;

  // XCD-aware swizzle: same-head blocks land on the same XCD
  const int b = blockIdx.x;            // 0..511
  const int pr = (b & 7) * 4 + ((b >> 3) & 3);
  const int qb = b >> 5;
  const size_t hb = (size_t)(pr >> 4) * 2048 * 1024 + (size_t)(pr & 15) * 64;
  const u16* Qh = Q + hb;
  const u16* Kh = K + hb;
  const u16* Vh = V + hb;
  u16* AOh = AO + hb;

  const int q0w = qb * 128 + wg * 32;
  const int kvb = grp * 1024;

  bf16x8 qf[4];
#pragma unroll
  for (int kk = 0; kk < 4; ++kk)
    qf[kk] = *(const bf16x8*)&Qh[(size_t)(q0w + l31) * 1024 + kk * 16 + hi * 8];

  f32x16 ot[2] = {};
  f32x16 sc[2];
  f32x8  Lacc = {};
  bf16x8 pa0[4], pa1[4];

  const int kxor = l31 & 7;
  const int kd0 = (l31 & 7) ^ (l31 >> 3);
  const int kv0 = (tg >> 3) * 2, d0 = (tg & 7) * 8;
  const int vg = (kv0 >> 4) * 2 + ((kv0 >> 2) & 1);
  const int vj = (kv0 & 3) + ((kv0 >> 3) & 1) * 4;

  auto VLOAD = [&](int tile, u16x8& a, u16x8& b_) {
    a  = *(const u16x8*)&Vh[(size_t)(kvb + tile * 64 + kv0) * 1024 + d0];
    b_ = *(const u16x8*)&Vh[(size_t)(kvb + tile * 64 + kv0 + 1) * 1024 + d0];
  };
  auto KSTAGE = [&](int tile, int buf) {
#pragma unroll
    for (int i = 0; i < 2; ++i) {
      int s = i * 256 + tg;
      int krow = s >> 3;
      int k2 = (s & 7) ^ (krow & 7);
      gload_lds16(&Kh[(size_t)(kvb + tile * 64 + krow) * 1024 + k2 * 8],
                  &Ks[grp][buf][(i * 256 + wg * 64) * 8]);
    }
  };
  auto VPACK = [&](u16x8 a, u16x8 b_, u16* dst) {
#pragma unroll
    for (int e = 0; e < 8; ++e) {
      int d = d0 + e;
      int key = ((d & 7) ^ (d >> 3)) & 7;
      int idx = d * 64 + ((vg ^ key) * 8) + vj;
      *(u32*)&dst[idx] = (u32)a[e] | ((u32)b_[e] << 16);
    }
  };
  auto QKT = [&](const u16* ks) {
    sc[0] = f32x16{};
    sc[1] = f32x16{};
    __builtin_amdgcn_s_setprio(1);
#pragma unroll
    for (int kk = 0; kk < 4; ++kk) {
      bf16x8 kf0 = *(const bf16x8*)&ks[l31 * 64 + (((kk * 2 + hi) ^ kxor) * 8)];
      bf16x8 kf1 = *(const bf16x8*)&ks[(32 + l31) * 64 + (((kk * 2 + hi) ^ kxor) * 8)];
      sc[0] = __builtin_amdgcn_mfma_f32_32x32x16_bf16(kf0, qf[kk], sc[0], 0, 0, 0);
      sc[1] = __builtin_amdgcn_mfma_f32_32x32x16_bf16(kf1, qf[kk], sc[1], 0, 0, 0);
    }
    __builtin_amdgcn_s_setprio(0);
  };
  auto PV = [&](const u16* vt, const bf16x8* pa) {
    __builtin_amdgcn_s_setprio(1);
#pragma unroll
    for (int kk = 0; kk < 4; ++kk) {
      bf16x8 vf0 = *(const bf16x8*)&vt[l31 * 64 + (((kk * 2 + hi) ^ kd0) * 8)];
      bf16x8 vf1 = *(const bf16x8*)&vt[(32 + l31) * 64 + (((kk * 2 + hi) ^ (kd0 ^ 4)) * 8)];
      ot[0] = __builtin_amdgcn_mfma_f32_32x32x16_bf16(vf0, pa[kk], ot[0], 0, 0, 0);
      ot[1] = __builtin_amdgcn_mfma_f32_32x32x16_bf16(vf1, pa[kk], ot[1], 0, 0, 0);
    }
    __builtin_amdgcn_s_setprio(0);
  };
  auto EXPPACK = [&](bf16x8* pa) {
#pragma unroll
    for (int fi = 0; fi < 2; ++fi)
#pragma unroll
      for (int r = 0; r < 16; ++r)
        sc[fi][r] = fexp(sc[fi][r]);
    {
      f32x8 lo0 = __builtin_shufflevector(sc[0], sc[0], 0,1,2,3,4,5,6,7);
      f32x8 hi0 = __builtin_shufflevector(sc[0], sc[0], 8,9,10,11,12,13,14,15);
      f32x8 lo1 = __builtin_shufflevector(sc[1], sc[1], 0,1,2,3,4,5,6,7);
      f32x8 hi1 = __builtin_shufflevector(sc[1], sc[1], 8,9,10,11,12,13,14,15);
      Lacc += (lo0 + hi0) + (lo1 + hi1);
    }
#pragma unroll
    for (int fi = 0; fi < 2; ++fi) {
      u32x4 w0 = {cvtpk(sc[fi][0],  sc[fi][1]),  cvtpk(sc[fi][2],  sc[fi][3]),
                  cvtpk(sc[fi][4],  sc[fi][5]),  cvtpk(sc[fi][6],  sc[fi][7])};
      u32x4 w1 = {cvtpk(sc[fi][8],  sc[fi][9]),  cvtpk(sc[fi][10], sc[fi][11]),
                  cvtpk(sc[fi][12], sc[fi][13]), cvtpk(sc[fi][14], sc[fi][15])};
      pa[2 * fi]     = __builtin_bit_cast(bf16x8, w0);
      pa[2 * fi + 1] = __builtin_bit_cast(bf16x8, w1);
    }
  };

  int vm1 = 2, v0 = 0, vp1 = 1;
  auto ROT = [&]() { int tmp = vm1; vm1 = v0; v0 = vp1; vp1 = tmp; };

  // ---- prologue: V[0] regs (oldest), K[0], K[1]; pack V[0]->buf0; S[0] ----
  {
    u16x8 a, b_;
    VLOAD(0, a, b_);
    __builtin_amdgcn_sched_barrier(0);
    KSTAGE(0, 0);
    KSTAGE(1, 1);
    VPACK(a, b_, &Vt3[grp][0][0]);                      // compiler waits vmcnt(4)
    asm volatile("s_waitcnt vmcnt(2)" ::: "memory");    // K[0] landed
    asm volatile("s_waitcnt lgkmcnt(0)" ::: "memory");
    __builtin_amdgcn_sched_barrier(0);
    __builtin_amdgcn_s_barrier();
    QKT(&Ks[grp][0][0]);                                // S[0]
    asm volatile("s_waitcnt lgkmcnt(0)" ::: "memory");
    __builtin_amdgcn_sched_barrier(0);
    __builtin_amdgcn_s_barrier();
  }

  // ---- steady loop: tt = 0..13 ----
  for (int tp = 0; tp < 7; ++tp) {
#pragma unroll
    for (int sub = 0; sub < 2; ++sub) {
      const int tt = 2 * tp + sub;
      u16x8 a, b_;
      VLOAD(tt + 1, a, b_);                             // oldest this iter
      __builtin_amdgcn_sched_barrier(0);
      KSTAGE(tt + 2, sub);                              // in flight across barrier
      if (tt >= 1) PV(&Vt3[grp][vm1][0], sub ? pa0 : pa1);
      EXPPACK(sub ? pa1 : pa0);
      asm volatile("s_waitcnt vmcnt(4)" ::: "memory");  // K[tt+1] landed
      QKT(&Ks[grp][sub ^ 1][0]);                        // S[tt+1]
      VPACK(a, b_, &Vt3[grp][vp1][0]);                  // compiler waits vmcnt(2)
      asm volatile("s_waitcnt lgkmcnt(0)" ::: "memory");
      __builtin_amdgcn_sched_barrier(0);
      __builtin_amdgcn_s_barrier();
      ROT();
    }
  }

  // ---- iter 14 (sub=0): no K prefetch ----
  {
    u16x8 a, b_;
    VLOAD(15, a, b_);
    __builtin_amdgcn_sched_barrier(0);
    PV(&Vt3[grp][vm1][0], pa1);
    EXPPACK(pa0);
    asm volatile("s_waitcnt vmcnt(2)" ::: "memory");    // K[15] landed
    QKT(&Ks[grp][1][0]);                                // S[15]
    VPACK(a, b_, &Vt3[grp][vp1][0]);                    // compiler waits vmcnt(0)
    asm volatile("s_waitcnt lgkmcnt(0)" ::: "memory");
    __builtin_amdgcn_sched_barrier(0);
    __builtin_amdgcn_s_barrier();
    ROT();
  }
  // ---- iter 15 (sub=1): PV(14), exp/pack(15) ----
  PV(&Vt3[grp][vm1][0], pa0);
  EXPPACK(pa1);
  ROT();
  // ---- final PV: P[15] x V[15] ----
  PV(&Vt3[grp][vm1][0], pa1);

  // ---- per-lane L partial ----
  float lp = (((Lacc[0] + Lacc[1]) + (Lacc[2] + Lacc[3])) +
              ((Lacc[4] + Lacc[5]) + (Lacc[6] + Lacc[7])));

  __syncthreads();
  float* Osh = (float*)&Ks[0][0][0];
  float* Lsh = (float*)&Vt3[0][0][0];
  const int pair = wg;
  const int obase = (((pair * 2 + hi) * 32) + l31) * 32;
  if (grp == 1) {
    *(f32x16*)&Osh[obase]      = ot[0];
    *(f32x16*)&Osh[obase + 16] = ot[1];
    Lsh[pair * 64 + lane] = lp;
  }
  __syncthreads();
  if (grp == 0) {
    ot[0] += *(const f32x16*)&Osh[obase];
    ot[1] += *(const f32x16*)&Osh[obase + 16];
    lp += Lsh[pair * 64 + lane];
    float L = xhalf_add(lp);
    float inv = 1.f / L;
    const size_t qrow = (size_t)(q0w + l31) * 1024;
#pragma unroll
    for (int dn = 0; dn < 2; ++dn)
#pragma unroll
      for (int j = 0; j < 8; ++j) {
        int r = 2 * j;
        int d = 2 * (j & 1) + 8 * (j >> 1) + 4 * hi + 32 * dn;
        u32 w = cvtpk(ot[dn][r] * inv, ot[dn][r + 1] * inv);
        *(u32*)&AOh[qrow + d] = w;
      }
  }
}

// ---------------------------------------------------------------------------
extern "C" void kernel_launch(void* const* d_in, const int* in_sizes, int n_in,
                              void* d_out, int out_size, void* d_ws, size_t ws_size,
                              hipStream_t stream) {
  const float* x  = (const float*)d_in[0];
  const float* wq = (const float*)d_in[1];
  const float* wk = (const float*)d_in[2];
  const float* wv = (const float*)d_in[3];
  const float* wo = (const float*)d_in[4];

  u16* ws = (u16*)d_ws;
  u16* xb  = ws;                 // 4194304  (x bf16)
  u16* wqb = ws + 4194304;       // 1048576
  u16* wkb = ws + 5242880;
  u16* wvb = ws + 6291456;
  u16* wob = ws + 7340032;
  u16* Qm  = ws + 8388608;       // 4194304
  u16* Km  = ws + 12582912;
  u16* Vm  = ws + 16777216;      // 4194304 (row-major V)
  u16* AOm = ws + 20971520;      // end at 25165824 u16 = 48 MiB

  cvt_all<<<2048, 256, 0, stream>>>(x, wq, wk, wv, wo, ws);
  gemm_qkv<<<768, 256, 0, stream>>>(xb, wqb, wkb, wvb, Qm, Km, Vm);
  attn_fwd<<<512, 512, 0, stream>>>(Qm, Km, Vm, AOm);
  gemm_out<<<512, 256, 0, stream>>>(AOm, wob, (float*)d_out);
}